// Round 6
// baseline (446.247 us; speedup 1.0000x reference)
//
#include <hip/hip_runtime.h>
#include <hip/hip_bf16.h>
#include <math.h>

typedef __attribute__((ext_vector_type(4))) float floatx4;
typedef __attribute__((ext_vector_type(16))) float floatx16;
typedef __attribute__((ext_vector_type(8))) __bf16 bf16x8;

__device__ __forceinline__ unsigned short f2bf(float f) {
    union { float f; unsigned int u; } v; v.f = f;
    unsigned int u = v.u;
    u += 0x7FFFu + ((u >> 16) & 1u);          // round-to-nearest-even
    return (unsigned short)(u >> 16);
}

__device__ __forceinline__ unsigned int pkbf(float a, float b) {
    return (unsigned int)f2bf(a) | ((unsigned int)f2bf(b) << 16);  // low16=a
}

// async global->LDS, 16B per lane; lds base must be wave-uniform
__device__ __forceinline__ void gl_lds16(const void* g, void* l) {
    __builtin_amdgcn_global_load_lds(
        (const __attribute__((address_space(1))) void*)g,
        (__attribute__((address_space(3))) void*)l, 16, 0, 0);
}

// ---------------------------------------------------------------- cast kernel
__global__ void cast_f32_bf16(const float* __restrict__ in,
                              unsigned short* __restrict__ out, int n) {
    int i = (blockIdx.x * blockDim.x + threadIdx.x) * 4;
    if (i + 4 <= n) {
        float4 f = *(const float4*)(in + i);
        ushort4 o;
        o.x = f2bf(f.x); o.y = f2bf(f.y); o.z = f2bf(f.z); o.w = f2bf(f.w);
        *(ushort4*)(out + i) = o;
    }
}

// ---------------------------------------------------------------- GEMM (NT)
// C[M,N] = A[M,K] * B[N,K]^T + bias[N]
// MODE 0: store fp32 to Cf.   MODE 1: scatter bf16 to q/k/vT (N==6144 path).
// NOTE: plain block mapping — the R3 group-swizzle scattered shared tiles
// across the 8 XCD L2s (FETCH 91->225 MB measured). Keep it simple.
#define BM 128
#define BN 128
#define BK 32

template<int MODE>
__global__ __launch_bounds__(256) void gemm_nt(
    const unsigned short* __restrict__ A,
    const unsigned short* __restrict__ B,
    const float* __restrict__ bias,
    float* __restrict__ Cf,
    unsigned short* __restrict__ q_ws,
    unsigned short* __restrict__ k_ws,
    unsigned short* __restrict__ vT_ws,
    int M, int N, int K)
{
    // UNPADDED: required by global_load_lds (wave-uniform base + lane*16)
    __shared__ unsigned short Asm[BM][BK];   // 8 KB
    __shared__ unsigned short Bsm[BN][BK];   // 8 KB

    const int bx = blockIdx.x, by = blockIdx.y;
    const int m0 = by * BM, n0 = bx * BN;
    const int tid = threadIdx.x;
    const int lane = tid & 63, wid = tid >> 6;
    const int quad = lane >> 4, li = lane & 15;
    const int wy = wid >> 1, wx = wid & 1;

    // staging geometry: each 1KB chunk = 16 rows x 64B; 8 chunks per tile
    const int lrow = lane >> 2;          // 0..15 row within chunk
    const int lcol = (lane & 3) * 8;     // ushort col 0,8,16,24

    floatx4 acc[4][4] = {};

    const int kTiles = K / BK;
    for (int kt = 0; kt < kTiles; ++kt) {
        const int k0 = kt * BK;
        #pragma unroll
        for (int c = 0; c < 2; ++c) {
            const int cidx = wid * 2 + c;            // 0..7
            const int row = cidx * 16 + lrow;        // 0..127
            gl_lds16(A + (size_t)(m0 + row) * K + k0 + lcol,
                     &Asm[0][0] + cidx * 512);
            gl_lds16(B + (size_t)(n0 + row) * K + k0 + lcol,
                     &Bsm[0][0] + cidx * 512);
        }
        __syncthreads();   // drains vmcnt(0) -> LDS tiles complete

        bf16x8 af[4], bfr[4];
        #pragma unroll
        for (int t = 0; t < 4; ++t) {
            af[t]  = *(const bf16x8*)(&Asm[wy * 64 + t * 16 + li][quad * 8]);
            bfr[t] = *(const bf16x8*)(&Bsm[wx * 64 + t * 16 + li][quad * 8]);
        }
        #pragma unroll
        for (int i = 0; i < 4; ++i)
            #pragma unroll
            for (int j = 0; j < 4; ++j)
                acc[i][j] = __builtin_amdgcn_mfma_f32_16x16x32_bf16(
                    af[i], bfr[j], acc[i][j], 0, 0, 0);
        __syncthreads();
    }

    // ---------------- epilogue
    if (MODE == 0) {
        #pragma unroll
        for (int i = 0; i < 4; ++i)
            #pragma unroll
            for (int j = 0; j < 4; ++j) {
                int col = wx * 64 + j * 16 + li;
                float bv = bias[n0 + col];
                #pragma unroll
                for (int r = 0; r < 4; ++r) {
                    int row = wy * 64 + i * 16 + quad * 4 + r;
                    Cf[(size_t)(m0 + row) * N + n0 + col] = acc[i][j][r] + bv;
                }
            }
    } else {
        // N = 6144 layout: bx in [0,48): which = bx>>4, h = bx&15, d = col
        const int which = bx >> 4;
        const int h = bx & 15;
        const int b = by >> 4;
        const int lbase = (by & 15) * BM;
        const size_t bh = (size_t)(b * 16 + h);
        #pragma unroll
        for (int i = 0; i < 4; ++i)
            #pragma unroll
            for (int j = 0; j < 4; ++j) {
                int col = wx * 64 + j * 16 + li;   // == d
                float bv = bias[n0 + col];
                #pragma unroll
                for (int r = 0; r < 4; ++r) {
                    int row = wy * 64 + i * 16 + quad * 4 + r;
                    int l = lbase + row;
                    unsigned short ob = f2bf(acc[i][j][r] + bv);
                    if (which == 0)      q_ws[(bh * 2048 + l) * 128 + col] = ob;
                    else if (which == 1) k_ws[(bh * 2048 + l) * 128 + col] = ob;
                    else                 vT_ws[(bh * 128 + col) * 2048 + l] = ob;
                }
            }
    }
}

// ---------------------------------------------------------------- attention
// 256 thr = 4 waves per block; block = one 128-row q-tile of one (b,h).
// Wave owns 32 q-rows. 32x32x16 MFMA. S^T = K*Q^T (softmax lane-local),
// O^T = V^T * P^T with P transposed S->B-frag via register shuffles.
// Keys processed in 64-wide chunks (2 per tile) to keep S live-range at
// 32 VGPRs — the R5 monolithic version spilled to scratch (VGPR capped 128,
// needed ~200: MfmaUtil 1.9%, 190 us of latency stall).
#define AP 8
__global__ __launch_bounds__(256, 1) void attn_kernel(
    const unsigned short* __restrict__ q_ws,
    const unsigned short* __restrict__ k_ws,
    const unsigned short* __restrict__ vT_ws,
    unsigned short* __restrict__ aout,
    const int* __restrict__ causal_ptr)
{
    __shared__ unsigned short Ksm[128][128 + AP];   // 34 KB (reused for O epilogue)
    __shared__ unsigned short Vsm[128][128 + AP];   // 34 KB, d-major (V^T)

    // balanced mapping: blocks c and c+256 sum to 17 tile-computes
    const int ord = blockIdx.x;
    int qt, bhid;
    if (ord < 256) { qt = ord >> 5;              bhid = ord & 31; }
    else           { qt = 15 - ((ord - 256) >> 5); bhid = ord & 31; }
    const int b = bhid >> 4, h = bhid & 15;

    const int tid = threadIdx.x;
    const int lane = tid & 63, w = tid >> 6;       // 4 waves
    const int lq = lane & 31;                      // q-col / row-in-tile
    const int half = lane >> 5;
    const size_t bh = (size_t)(b * 16 + h);
    const unsigned short* Qp = q_ws + bh * 2048 * 128;
    const unsigned short* Kp = k_ws + bh * 2048 * 128;
    const unsigned short* Vp = vT_ws + bh * 128 * 2048;
    const int causal = causal_ptr[0];
    const float scale = 0.08838834764831845f;      // 1/sqrt(128)

    // Q^T B-operand frags (persist): qf[s][j] = Q[qg][16s + 8*half + j]
    const int qg = qt * 128 + w * 32 + lq;
    bf16x8 qf[8];
    #pragma unroll
    for (int s = 0; s < 8; ++s)
        qf[s] = *(const bf16x8*)(Qp + (size_t)qg * 128 + s * 16 + half * 8);

    floatx16 O[4] = {};
    float m_i = -INFINITY, l_i = 0.f;

    const int myEnd = causal ? qt : 15;
    for (int kt = 0; kt <= myEnd; ++kt) {
        // stage K [key][d] and V^T [d][key] tiles: 2048 x 16B chunks
        #pragma unroll
        for (int c = 0; c < 8; ++c) {
            int chunk = c * 256 + tid;            // 0..2047
            int row = chunk >> 4;                 // 0..127
            int cc  = (chunk & 15) * 8;           // ushort col 0..120
            *(uint4*)(&Ksm[row][cc]) =
                *(const uint4*)(Kp + (size_t)(kt * 128 + row) * 128 + cc);
            *(uint4*)(&Vsm[row][cc]) =
                *(const uint4*)(Vp + (size_t)row * 2048 + kt * 128 + cc);
        }
        __syncthreads();

        const bool diag = causal && (kt == qt);
        // two 64-key chunks; online-softmax update per chunk (S live = 32 regs)
        #pragma unroll 1
        for (int ch = 0; ch < 2; ++ch) {
            // S^T[key][q] for keys 64*ch .. 64*ch+63
            floatx16 S[2] = {};
            #pragma unroll
            for (int c2 = 0; c2 < 2; ++c2) {
                const int ct = ch * 2 + c2;
                #pragma unroll
                for (int s = 0; s < 8; ++s) {
                    bf16x8 kf = *(const bf16x8*)(&Ksm[ct * 32 + lq][s * 16 + half * 8]);
                    S[c2] = __builtin_amdgcn_mfma_f32_32x32x16_bf16(kf, qf[s], S[c2], 0, 0, 0);
                }
            }

            // scale + causal mask; row stats are LANE-LOCAL (col of S^T = q)
            float mx = -INFINITY;
            #pragma unroll
            for (int c2 = 0; c2 < 2; ++c2)
                #pragma unroll
                for (int r = 0; r < 16; ++r) {
                    float sv = S[c2][r] * scale;
                    if (diag) {
                        int key = 32 * (ch * 2 + c2) + (r & 3) + 8 * (r >> 2) + 4 * half;
                        if (kt * 128 + key > qg) sv = -INFINITY;
                    }
                    S[c2][r] = sv;
                    mx = fmaxf(mx, sv);
                }
            mx = fmaxf(mx, __shfl_xor(mx, 32, 64));   // combine key-halves
            float m_new = fmaxf(m_i, mx);
            // armor: fully-masked chunk (q<64 on diag ch=1) -> keep finite base
            float m_use = (m_new == -INFINITY) ? 0.f : m_new;
            float alpha = __expf(m_i - m_use);

            float rs = 0.f;
            #pragma unroll
            for (int c2 = 0; c2 < 2; ++c2)
                #pragma unroll
                for (int r = 0; r < 16; ++r) {
                    float p = __expf(S[c2][r] - m_use);
                    S[c2][r] = p;
                    rs += p;
                }
            rs += __shfl_xor(rs, 32, 64);
            l_i = l_i * alpha + rs;
            m_i = (m_new == -INFINITY) ? m_i : m_new;
            #pragma unroll
            for (int dt = 0; dt < 4; ++dt)
                #pragma unroll
                for (int r = 0; r < 16; ++r)
                    O[dt][r] *= alpha;

            // P^T -> B-operand frags via register half-swap (no LDS round-trip)
            bf16x8 pfr[4];
            #pragma unroll
            for (int c2 = 0; c2 < 2; ++c2)
                #pragma unroll
                for (int h2 = 0; h2 < 2; ++h2) {
                    int base = 8 * h2;
                    unsigned int pk0 = pkbf(S[c2][base + 0], S[c2][base + 1]);
                    unsigned int pk1 = pkbf(S[c2][base + 2], S[c2][base + 3]);
                    unsigned int pk2 = pkbf(S[c2][base + 4], S[c2][base + 5]);
                    unsigned int pk3 = pkbf(S[c2][base + 6], S[c2][base + 7]);
                    unsigned int x0 = __shfl_xor((int)pk0, 32, 64);
                    unsigned int x1 = __shfl_xor((int)pk1, 32, 64);
                    unsigned int x2 = __shfl_xor((int)pk2, 32, 64);
                    unsigned int x3 = __shfl_xor((int)pk3, 32, 64);
                    union { unsigned int u[4]; bf16x8 v; } fr;
                    fr.u[0] = half ? x2 : pk0;
                    fr.u[1] = half ? x3 : pk1;
                    fr.u[2] = half ? pk2 : x0;
                    fr.u[3] = half ? pk3 : x1;
                    pfr[c2 * 2 + h2] = fr.v;
                }

            // O^T[d][q] += V^T * P^T over this chunk's 64 keys
            #pragma unroll
            for (int dt = 0; dt < 4; ++dt)
                #pragma unroll
                for (int p = 0; p < 4; ++p) {
                    int s = ch * 4 + p;
                    bf16x8 vf = *(const bf16x8*)(&Vsm[dt * 32 + lq][s * 16 + half * 8]);
                    O[dt] = __builtin_amdgcn_mfma_f32_32x32x16_bf16(vf, pfr[p], O[dt], 0, 0, 0);
                }
        }
        __syncthreads();   // before next tile restages K/V
    }

    // epilogue: normalize, transpose O^T->[q][d] via Ksm, coalesced store
    const float invl = 1.0f / l_i;
    #pragma unroll
    for (int dt = 0; dt < 4; ++dt)
        #pragma unroll
        for (int g = 0; g < 4; ++g) {
            int dbase = dt * 32 + g * 8 + half * 4;
            ushort4 o4;
            o4.x = f2bf(O[dt][g * 4 + 0] * invl);
            o4.y = f2bf(O[dt][g * 4 + 1] * invl);
            o4.z = f2bf(O[dt][g * 4 + 2] * invl);
            o4.w = f2bf(O[dt][g * 4 + 3] * invl);
            *(ushort4*)(&Ksm[w * 32 + lq][dbase]) = o4;
        }
    __syncthreads();
    #pragma unroll
    for (int c = 0; c < 8; ++c) {
        int chunk = c * 256 + tid;                // 0..2047
        int row = chunk >> 4;                     // 0..127 (q within tile)
        int dc = (chunk & 15) * 8;
        uint4 v = *(const uint4*)(&Ksm[row][dc]);
        *(uint4*)(aout + ((size_t)b * 2048 + qt * 128 + row) * 2048 + h * 128 + dc) = v;
    }
}

// ---------------------------------------------------------------- launch
extern "C" void kernel_launch(void* const* d_in, const int* in_sizes, int n_in,
                              void* d_out, int out_size, void* d_ws, size_t ws_size,
                              hipStream_t stream) {
    const float* x     = (const float*)d_in[0];
    const float* w_in  = (const float*)d_in[1];
    const float* b_in  = (const float*)d_in[2];
    const float* w_out = (const float*)d_in[3];
    const float* b_out = (const float*)d_in[4];
    const int* causal  = (const int*)d_in[5];

    char* ws = (char*)d_ws;
    unsigned short* xb    = (unsigned short*)ws; ws += (size_t)4096 * 2048 * 2;
    unsigned short* wb    = (unsigned short*)ws; ws += (size_t)6144 * 2048 * 2;
    unsigned short* wob   = (unsigned short*)ws; ws += (size_t)2048 * 2048 * 2;
    unsigned short* q_ws  = (unsigned short*)ws; ws += (size_t)32 * 2048 * 128 * 2;
    unsigned short* k_ws  = (unsigned short*)ws; ws += (size_t)32 * 2048 * 128 * 2;
    unsigned short* vT_ws = (unsigned short*)ws; ws += (size_t)32 * 2048 * 128 * 2;
    unsigned short* aout  = (unsigned short*)ws; ws += (size_t)4096 * 2048 * 2;

    cast_f32_bf16<<<8192, 256, 0, stream>>>(x, xb, 4096 * 2048);
    cast_f32_bf16<<<12288, 256, 0, stream>>>(w_in, wb, 6144 * 2048);
    cast_f32_bf16<<<4096, 256, 0, stream>>>(w_out, wob, 2048 * 2048);

    gemm_nt<1><<<dim3(48, 32), 256, 0, stream>>>(
        xb, wb, b_in, nullptr, q_ws, k_ws, vT_ws, 4096, 6144, 2048);

    attn_kernel<<<512, 256, 0, stream>>>(
        q_ws, k_ws, vT_ws, aout, causal);

    gemm_nt<0><<<dim3(16, 32), 256, 0, stream>>>(
        aout, wob, b_out, (float*)d_out, nullptr, nullptr, nullptr,
        4096, 2048, 2048);
}

// Round 7
// 443.038 us; speedup vs baseline: 1.0072x; 1.0072x over previous
//
#include <hip/hip_runtime.h>
#include <hip/hip_bf16.h>
#include <math.h>

typedef __attribute__((ext_vector_type(4))) float floatx4;
typedef __attribute__((ext_vector_type(16))) float floatx16;
typedef __attribute__((ext_vector_type(8))) __bf16 bf16x8;

__device__ __forceinline__ unsigned short f2bf(float f) {
    union { float f; unsigned int u; } v; v.f = f;
    unsigned int u = v.u;
    u += 0x7FFFu + ((u >> 16) & 1u);          // round-to-nearest-even
    return (unsigned short)(u >> 16);
}

__device__ __forceinline__ unsigned int pkbf(float a, float b) {
    return (unsigned int)f2bf(a) | ((unsigned int)f2bf(b) << 16);  // low16=a
}

// async global->LDS, 16B per lane; lds base must be wave-uniform
__device__ __forceinline__ void gl_lds16(const void* g, void* l) {
    __builtin_amdgcn_global_load_lds(
        (const __attribute__((address_space(1))) void*)g,
        (__attribute__((address_space(3))) void*)l, 16, 0, 0);
}

// ---------------------------------------------------------------- cast kernel
__global__ void cast_f32_bf16(const float* __restrict__ in,
                              unsigned short* __restrict__ out, int n) {
    int i = (blockIdx.x * blockDim.x + threadIdx.x) * 4;
    if (i + 4 <= n) {
        float4 f = *(const float4*)(in + i);
        ushort4 o;
        o.x = f2bf(f.x); o.y = f2bf(f.y); o.z = f2bf(f.z); o.w = f2bf(f.w);
        *(ushort4*)(out + i) = o;
    }
}

// ---------------------------------------------------------------- GEMM (NT)
// C[M,N] = A[M,K] * B[N,K]^T + bias[N]
// MODE 0: store fp32 to Cf.   MODE 1: scatter bf16 to q/k/vT (N==6144 path).
// BK=64 (m97 config, halves barriers) + XOR-swizzled LDS: physical slot of
// (row, col8) is row*128B + (col8 ^ (row&7))*16B. Legal with global_load_lds
// (LDS dst fixed per lane; we permute the GLOBAL source instead). Fragment
// reads then spread all 32 banks -> kills the 8-way conflict (1.26e7 meas).
#define BM 128
#define BN 128
#define BK 64

template<int MODE>
__global__ __launch_bounds__(256) void gemm_nt(
    const unsigned short* __restrict__ A,
    const unsigned short* __restrict__ B,
    const float* __restrict__ bias,
    float* __restrict__ Cf,
    unsigned short* __restrict__ q_ws,
    unsigned short* __restrict__ k_ws,
    unsigned short* __restrict__ vT_ws,
    int M, int N, int K)
{
    __shared__ unsigned short Asm[BM][BK];   // 16 KB
    __shared__ unsigned short Bsm[BN][BK];   // 16 KB

    const int bx = blockIdx.x, by = blockIdx.y;
    const int m0 = by * BM, n0 = bx * BN;
    const int tid = threadIdx.x;
    const int lane = tid & 63, wid = tid >> 6;
    const int quad = lane >> 4, li = lane & 15;
    const int wy = wid >> 1, wx = wid & 1;

    // staging: 16 instructions x 1KB; inst i covers rows i*8..i*8+7.
    // lane l -> row i*8 + (l>>3), swizzled col ((l&7) ^ (l>>3)) * 8
    const int lrow8 = lane >> 3;                    // 0..7
    const int lswz  = ((lane & 7) ^ lrow8) * 8;     // ushort col in global

    floatx4 acc[4][4] = {};

    const int kTiles = K / BK;
    for (int kt = 0; kt < kTiles; ++kt) {
        const int k0 = kt * BK;
        #pragma unroll
        for (int c = 0; c < 4; ++c) {
            const int inst = wid * 4 + c;            // 0..15
            const int row = inst * 8 + lrow8;        // 0..127
            gl_lds16(A + (size_t)(m0 + row) * K + k0 + lswz,
                     (char*)&Asm[0][0] + inst * 1024);
            gl_lds16(B + (size_t)(n0 + row) * K + k0 + lswz,
                     (char*)&Bsm[0][0] + inst * 1024);
        }
        __syncthreads();   // drains vmcnt(0) -> LDS tiles complete

        #pragma unroll
        for (int s2 = 0; s2 < 2; ++s2) {
            bf16x8 af[4], bfr[4];
            #pragma unroll
            for (int t = 0; t < 4; ++t) {
                const int col8 = s2 * 4 + quad;
                const int cswz = (col8 ^ (li & 7)) * 8;
                af[t]  = *(const bf16x8*)(&Asm[wy * 64 + t * 16 + li][cswz]);
                bfr[t] = *(const bf16x8*)(&Bsm[wx * 64 + t * 16 + li][cswz]);
            }
            #pragma unroll
            for (int i = 0; i < 4; ++i)
                #pragma unroll
                for (int j = 0; j < 4; ++j)
                    acc[i][j] = __builtin_amdgcn_mfma_f32_16x16x32_bf16(
                        af[i], bfr[j], acc[i][j], 0, 0, 0);
        }
        __syncthreads();
    }

    // ---------------- epilogue
    if (MODE == 0) {
        #pragma unroll
        for (int i = 0; i < 4; ++i)
            #pragma unroll
            for (int j = 0; j < 4; ++j) {
                int col = wx * 64 + j * 16 + li;
                float bv = bias[n0 + col];
                #pragma unroll
                for (int r = 0; r < 4; ++r) {
                    int row = wy * 64 + i * 16 + quad * 4 + r;
                    Cf[(size_t)(m0 + row) * N + n0 + col] = acc[i][j][r] + bv;
                }
            }
    } else {
        // N = 6144 layout: bx in [0,48): which = bx>>4, h = bx&15, d = col
        const int which = bx >> 4;
        const int h = bx & 15;
        const int b = by >> 4;
        const int lbase = (by & 15) * BM;
        const size_t bh = (size_t)(b * 16 + h);
        #pragma unroll
        for (int i = 0; i < 4; ++i)
            #pragma unroll
            for (int j = 0; j < 4; ++j) {
                int col = wx * 64 + j * 16 + li;   // == d
                float bv = bias[n0 + col];
                #pragma unroll
                for (int r = 0; r < 4; ++r) {
                    int row = wy * 64 + i * 16 + quad * 4 + r;
                    int l = lbase + row;
                    unsigned short ob = f2bf(acc[i][j][r] + bv);
                    if (which == 0)      q_ws[(bh * 2048 + l) * 128 + col] = ob;
                    else if (which == 1) k_ws[(bh * 2048 + l) * 128 + col] = ob;
                    else                 vT_ws[(bh * 128 + col) * 2048 + l] = ob;
                }
            }
    }
}

// ---------------------------------------------------------------- attention
// 256 thr = 4 waves per block; block = one 128-row q-tile of one (b,h).
// XCD-affinity swizzle: ord&7 selects XCD (dispatch round-robins blockIdx
// over the 8 XCDs); we pin bh>>2 == ord&7 so each XCD's L2 (4 MB) holds
// exactly its 4 bh's K+V (4 MB) -> K/V served from L2, not L3 (R5/R6 attn
// was ~185us at 1.5 TB/s effective with every pipe <4% busy = L3 thrash).
#define AP 8
__global__ __launch_bounds__(256, 1) void attn_kernel(
    const unsigned short* __restrict__ q_ws,
    const unsigned short* __restrict__ k_ws,
    const unsigned short* __restrict__ vT_ws,
    unsigned short* __restrict__ aout,
    const int* __restrict__ causal_ptr)
{
    __shared__ unsigned short Ksm[128][128 + AP];   // 34 KB (reused for O epilogue)
    __shared__ unsigned short Vsm[128][128 + AP];   // 34 KB, d-major (V^T)

    const int ord = blockIdx.x;
    const int xcd = ord & 7;
    const int slot = ord >> 3;            // 0..63
    const int bhl = slot & 3;             // which of this XCD's 4 bh
    const int sq = slot >> 2;             // 0..15
    const int qt = (sq & 1) ? (15 - (sq >> 1)) : (sq >> 1);  // balance heavy/light
    const int bhid = xcd * 4 + bhl;       // bh>>2 == xcd
    const int b = bhid >> 4, h = bhid & 15;

    const int tid = threadIdx.x;
    const int lane = tid & 63, w = tid >> 6;       // 4 waves
    const int lq = lane & 31;                      // q-col / row-in-tile
    const int half = lane >> 5;
    const size_t bh = (size_t)bhid;
    const unsigned short* Qp = q_ws + bh * 2048 * 128;
    const unsigned short* Kp = k_ws + bh * 2048 * 128;
    const unsigned short* Vp = vT_ws + bh * 128 * 2048;
    const int causal = causal_ptr[0];
    const float scale = 0.08838834764831845f;      // 1/sqrt(128)

    // Q^T B-operand frags (persist): qf[s][j] = Q[qg][16s + 8*half + j]
    const int qg = qt * 128 + w * 32 + lq;
    bf16x8 qf[8];
    #pragma unroll
    for (int s = 0; s < 8; ++s)
        qf[s] = *(const bf16x8*)(Qp + (size_t)qg * 128 + s * 16 + half * 8);

    floatx16 O[4] = {};
    float m_i = -INFINITY, l_i = 0.f;

    const int myEnd = causal ? qt : 15;
    for (int kt = 0; kt <= myEnd; ++kt) {
        // stage K [key][d] and V^T [d][key] tiles: 2048 x 16B chunks
        #pragma unroll
        for (int c = 0; c < 8; ++c) {
            int chunk = c * 256 + tid;            // 0..2047
            int row = chunk >> 4;                 // 0..127
            int cc  = (chunk & 15) * 8;           // ushort col 0..120
            *(uint4*)(&Ksm[row][cc]) =
                *(const uint4*)(Kp + (size_t)(kt * 128 + row) * 128 + cc);
            *(uint4*)(&Vsm[row][cc]) =
                *(const uint4*)(Vp + (size_t)row * 2048 + kt * 128 + cc);
        }
        __syncthreads();

        const bool diag = causal && (kt == qt);
        // two 64-key chunks; online-softmax update per chunk (S live = 32 regs)
        #pragma unroll 1
        for (int ch = 0; ch < 2; ++ch) {
            // S^T[key][q] for keys 64*ch .. 64*ch+63
            floatx16 S[2] = {};
            #pragma unroll
            for (int c2 = 0; c2 < 2; ++c2) {
                const int ct = ch * 2 + c2;
                #pragma unroll
                for (int s = 0; s < 8; ++s) {
                    bf16x8 kf = *(const bf16x8*)(&Ksm[ct * 32 + lq][s * 16 + half * 8]);
                    S[c2] = __builtin_amdgcn_mfma_f32_32x32x16_bf16(kf, qf[s], S[c2], 0, 0, 0);
                }
            }

            // scale + causal mask; row stats are LANE-LOCAL (col of S^T = q)
            float mx = -INFINITY;
            #pragma unroll
            for (int c2 = 0; c2 < 2; ++c2)
                #pragma unroll
                for (int r = 0; r < 16; ++r) {
                    float sv = S[c2][r] * scale;
                    if (diag) {
                        int key = 32 * (ch * 2 + c2) + (r & 3) + 8 * (r >> 2) + 4 * half;
                        if (kt * 128 + key > qg) sv = -INFINITY;
                    }
                    S[c2][r] = sv;
                    mx = fmaxf(mx, sv);
                }
            mx = fmaxf(mx, __shfl_xor(mx, 32, 64));   // combine key-halves
            float m_new = fmaxf(m_i, mx);
            // armor: fully-masked chunk (q<64 on diag ch=1) -> keep finite base
            float m_use = (m_new == -INFINITY) ? 0.f : m_new;
            float alpha = __expf(m_i - m_use);

            float rs = 0.f;
            #pragma unroll
            for (int c2 = 0; c2 < 2; ++c2)
                #pragma unroll
                for (int r = 0; r < 16; ++r) {
                    float p = __expf(S[c2][r] - m_use);
                    S[c2][r] = p;
                    rs += p;
                }
            rs += __shfl_xor(rs, 32, 64);
            l_i = l_i * alpha + rs;
            m_i = (m_new == -INFINITY) ? m_i : m_new;
            #pragma unroll
            for (int dt = 0; dt < 4; ++dt)
                #pragma unroll
                for (int r = 0; r < 16; ++r)
                    O[dt][r] *= alpha;

            // P^T -> B-operand frags via register half-swap (no LDS round-trip)
            bf16x8 pfr[4];
            #pragma unroll
            for (int c2 = 0; c2 < 2; ++c2)
                #pragma unroll
                for (int h2 = 0; h2 < 2; ++h2) {
                    int base = 8 * h2;
                    unsigned int pk0 = pkbf(S[c2][base + 0], S[c2][base + 1]);
                    unsigned int pk1 = pkbf(S[c2][base + 2], S[c2][base + 3]);
                    unsigned int pk2 = pkbf(S[c2][base + 4], S[c2][base + 5]);
                    unsigned int pk3 = pkbf(S[c2][base + 6], S[c2][base + 7]);
                    unsigned int x0 = __shfl_xor((int)pk0, 32, 64);
                    unsigned int x1 = __shfl_xor((int)pk1, 32, 64);
                    unsigned int x2 = __shfl_xor((int)pk2, 32, 64);
                    unsigned int x3 = __shfl_xor((int)pk3, 32, 64);
                    union { unsigned int u[4]; bf16x8 v; } fr;
                    fr.u[0] = half ? x2 : pk0;
                    fr.u[1] = half ? x3 : pk1;
                    fr.u[2] = half ? pk2 : x0;
                    fr.u[3] = half ? pk3 : x1;
                    pfr[c2 * 2 + h2] = fr.v;
                }

            // O^T[d][q] += V^T * P^T over this chunk's 64 keys
            #pragma unroll
            for (int dt = 0; dt < 4; ++dt)
                #pragma unroll
                for (int p = 0; p < 4; ++p) {
                    int s = ch * 4 + p;
                    bf16x8 vf = *(const bf16x8*)(&Vsm[dt * 32 + lq][s * 16 + half * 8]);
                    O[dt] = __builtin_amdgcn_mfma_f32_32x32x16_bf16(vf, pfr[p], O[dt], 0, 0, 0);
                }
        }
        __syncthreads();   // before next tile restages K/V
    }

    // epilogue: normalize, transpose O^T->[q][d] via Ksm, coalesced store
    const float invl = 1.0f / l_i;
    #pragma unroll
    for (int dt = 0; dt < 4; ++dt)
        #pragma unroll
        for (int g = 0; g < 4; ++g) {
            int dbase = dt * 32 + g * 8 + half * 4;
            ushort4 o4;
            o4.x = f2bf(O[dt][g * 4 + 0] * invl);
            o4.y = f2bf(O[dt][g * 4 + 1] * invl);
            o4.z = f2bf(O[dt][g * 4 + 2] * invl);
            o4.w = f2bf(O[dt][g * 4 + 3] * invl);
            *(ushort4*)(&Ksm[w * 32 + lq][dbase]) = o4;
        }
    __syncthreads();
    #pragma unroll
    for (int c = 0; c < 8; ++c) {
        int chunk = c * 256 + tid;                // 0..2047
        int row = chunk >> 4;                     // 0..127 (q within tile)
        int dc = (chunk & 15) * 8;
        uint4 v = *(const uint4*)(&Ksm[row][dc]);
        *(uint4*)(aout + ((size_t)b * 2048 + qt * 128 + row) * 2048 + h * 128 + dc) = v;
    }
}

// ---------------------------------------------------------------- launch
extern "C" void kernel_launch(void* const* d_in, const int* in_sizes, int n_in,
                              void* d_out, int out_size, void* d_ws, size_t ws_size,
                              hipStream_t stream) {
    const float* x     = (const float*)d_in[0];
    const float* w_in  = (const float*)d_in[1];
    const float* b_in  = (const float*)d_in[2];
    const float* w_out = (const float*)d_in[3];
    const float* b_out = (const float*)d_in[4];
    const int* causal  = (const int*)d_in[5];

    char* ws = (char*)d_ws;
    unsigned short* xb    = (unsigned short*)ws; ws += (size_t)4096 * 2048 * 2;
    unsigned short* wb    = (unsigned short*)ws; ws += (size_t)6144 * 2048 * 2;
    unsigned short* wob   = (unsigned short*)ws; ws += (size_t)2048 * 2048 * 2;
    unsigned short* q_ws  = (unsigned short*)ws; ws += (size_t)32 * 2048 * 128 * 2;
    unsigned short* k_ws  = (unsigned short*)ws; ws += (size_t)32 * 2048 * 128 * 2;
    unsigned short* vT_ws = (unsigned short*)ws; ws += (size_t)32 * 2048 * 128 * 2;
    unsigned short* aout  = (unsigned short*)ws; ws += (size_t)4096 * 2048 * 2;

    cast_f32_bf16<<<8192, 256, 0, stream>>>(x, xb, 4096 * 2048);
    cast_f32_bf16<<<12288, 256, 0, stream>>>(w_in, wb, 6144 * 2048);
    cast_f32_bf16<<<4096, 256, 0, stream>>>(w_out, wob, 2048 * 2048);

    gemm_nt<1><<<dim3(48, 32), 256, 0, stream>>>(
        xb, wb, b_in, nullptr, q_ws, k_ws, vT_ws, 4096, 6144, 2048);

    attn_kernel<<<512, 256, 0, stream>>>(
        q_ws, k_ws, vT_ws, aout, causal);

    gemm_nt<0><<<dim3(16, 32), 256, 0, stream>>>(
        aout, wob, b_out, (float*)d_out, nullptr, nullptr, nullptr,
        4096, 2048, 2048);
}